// Round 2
// baseline (1105.312 us; speedup 1.0000x reference)
//
#include <hip/hip_runtime.h>

// EUNN: 256 layers; each layer = rotation on even pairs (2i,2i+1), then
// rotation on odd pairs (2i+1,2i+2 mod H).
// Pair math: y0 = e^{i*phi} (ct*u - st*v); y1 = st*u + ct*v.

#define H_DIM 1024
#define C2 256
#define RPW 2   // batch rows per wave

// coef layout: [c][phase][j][lane] as float4 (ct, st, cp, sp), pair i = 8*lane + j
// -> flat float4 index: ((c*2 + phase)*8 + j)*64 + lane,  4 MB total.

__global__ __launch_bounds__(256) void eunn_coef_kernel(
    const float* __restrict__ phi0, const float* __restrict__ theta0,
    const float* __restrict__ phi1, const float* __restrict__ theta1,
    float4* __restrict__ coef) {
    int t = blockIdx.x * 256 + threadIdx.x;     // [0, 256*2*512)
    int i = t & 511;                            // pair index
    int p = (t >> 9) & 1;                       // phase (0: even pairs, 1: odd pairs)
    int c = t >> 10;                            // layer
    const float* phi   = p ? phi1   : phi0;
    const float* theta = p ? theta1 : theta0;
    float ph = phi[i * C2 + c];
    float th = theta[i * C2 + c];
    float sp, cp, st, ct;
    __sincosf(ph, &sp, &cp);
    __sincosf(th, &st, &ct);
    int j = i & 7;
    int l = i >> 3;
    coef[(((c * 2 + p) * 8) + j) * 64 + l] = make_float4(ct, st, cp, sp);
}

__device__ __forceinline__ void rot_pair(const float4 q,
                                         float& ur, float& ui,
                                         float& wr, float& wi) {
    // q = (ct, st, cp, sp)
    float ar = fmaf(-q.y, wr, q.x * ur);   // ct*u - st*v (real part)
    float ai = fmaf(-q.y, wi, q.x * ui);
    float br = fmaf( q.x, wr, q.y * ur);   // st*u + ct*v
    float bi = fmaf( q.x, wi, q.y * ui);
    ur = fmaf(-q.w, ai, q.z * ar);         // e^{i phi} * a
    ui = fmaf( q.w, ar, q.z * ai);
    wr = br;
    wi = bi;
}

__global__ __launch_bounds__(256, 2) void eunn_main_kernel(
    const float* __restrict__ x,
    const float4* __restrict__ coef,
    float* __restrict__ out) {
    const int lane = threadIdx.x & 63;
    const int wave = threadIdx.x >> 6;
    const int row0 = (blockIdx.x * 4 + wave) * RPW;

    // lane owns complex elements [16*lane, 16*lane+16) of each of its RPW rows
    float vr[RPW][16], vi[RPW][16];

#pragma unroll
    for (int r = 0; r < RPW; ++r) {
        const float4* src = (const float4*)(x + (size_t)(row0 + r) * (H_DIM * 2)) + lane * 8;
#pragma unroll
        for (int m = 0; m < 8; ++m) {
            float4 f = src[m];
            vr[r][2 * m]     = f.x; vi[r][2 * m]     = f.y;
            vr[r][2 * m + 1] = f.z; vi[r][2 * m + 1] = f.w;
        }
    }

    // double-buffered per-layer coefficients in registers.
    // q[0..7]  : phase A pairs (local 2j,2j+1)
    // q[8..14] : phase B internal pairs (local 2j+1,2j+2)
    // q[15]    : phase B boundary pair owned by this lane (elem15, next lane's elem0)
    // q[16]    : phase B boundary pair of lane-1 (only .x=ct', .y=st' used)
    float4 qa[17], qb[17];

    auto load_coefs = [&](float4* q, int c) {
        const float4* ca = coef + (size_t)c * 1024;
#pragma unroll
        for (int j = 0; j < 16; ++j) q[j] = ca[j * 64 + lane];
        q[16] = ca[15 * 64 + ((lane + 63) & 63)];
    };

    auto do_layer = [&](const float4* q) {
        // phase A boundary-adjacent pairs first (j=0 and j=7), so the
        // cross-lane shuffles can issue early and their latency hides under
        // the remaining independent FMA work.
#pragma unroll
        for (int r = 0; r < RPW; ++r) {
            rot_pair(q[0], vr[r][0],  vi[r][0],  vr[r][1],  vi[r][1]);
            rot_pair(q[7], vr[r][14], vi[r][14], vr[r][15], vi[r][15]);
        }
        float nbr[RPW], nbi[RPW], pbr[RPW], pbi[RPW];
#pragma unroll
        for (int r = 0; r < RPW; ++r) {
            nbr[r] = __shfl(vr[r][0],  (lane + 1)  & 63);   // next lane's elem0 (post-A)
            nbi[r] = __shfl(vi[r][0],  (lane + 1)  & 63);
            pbr[r] = __shfl(vr[r][15], (lane + 63) & 63);   // prev lane's elem15 (post-A)
            pbi[r] = __shfl(vi[r][15], (lane + 63) & 63);
        }
        // phase A remaining pairs j=1..6
#pragma unroll
        for (int j = 1; j < 7; ++j) {
#pragma unroll
            for (int r = 0; r < RPW; ++r) {
                rot_pair(q[j], vr[r][2 * j],     vi[r][2 * j],
                               vr[r][2 * j + 1], vi[r][2 * j + 1]);
            }
        }
        // phase B internal pairs (local 2j+1, 2j+2), j=0..6
#pragma unroll
        for (int j = 0; j < 7; ++j) {
#pragma unroll
            for (int r = 0; r < RPW; ++r) {
                rot_pair(q[8 + j], vr[r][2 * j + 1], vi[r][2 * j + 1],
                                   vr[r][2 * j + 2], vi[r][2 * j + 2]);
            }
        }
        // phase B boundary: pair (my elem15, next lane's elem0), computed
        // locally on both sides from the pre-issued shuffles.
        const float4 qq = q[15];
        const float4 qp = q[16];
#pragma unroll
        for (int r = 0; r < RPW; ++r) {
            // new elem15 = e^{i phi}(ct*e15 - st*next_e0)
            float ar = fmaf(-qq.y, nbr[r], qq.x * vr[r][15]);
            float ai = fmaf(-qq.y, nbi[r], qq.x * vi[r][15]);
            vr[r][15] = fmaf(-qq.w, ai, qq.z * ar);
            vi[r][15] = fmaf( qq.w, ar, qq.z * ai);
            // new elem0 = st'*prev_e15 + ct'*e0   (lane-1's pair, real row)
            float b0r = fmaf(qp.x, vr[r][0], qp.y * pbr[r]);
            float b0i = fmaf(qp.x, vi[r][0], qp.y * pbi[r]);
            vr[r][0] = b0r; vi[r][0] = b0i;
        }
    };

    load_coefs(qa, 0);
#pragma unroll 1
    for (int c = 0; c < C2; c += 2) {
        load_coefs(qb, c + 1);
        do_layer(qa);
        load_coefs(qa, (c + 2 < C2) ? (c + 2) : 0);  // last reload is dummy
        do_layer(qb);
    }

#pragma unroll
    for (int r = 0; r < RPW; ++r) {
        float4* dst = (float4*)(out + (size_t)(row0 + r) * (H_DIM * 2)) + lane * 8;
#pragma unroll
        for (int m = 0; m < 8; ++m) {
            dst[m] = make_float4(vr[r][2 * m],     vi[r][2 * m],
                                 vr[r][2 * m + 1], vi[r][2 * m + 1]);
        }
    }
}

extern "C" void kernel_launch(void* const* d_in, const int* in_sizes, int n_in,
                              void* d_out, int out_size, void* d_ws, size_t ws_size,
                              hipStream_t stream) {
    const float* x      = (const float*)d_in[0];
    const float* phi0   = (const float*)d_in[1];
    const float* theta0 = (const float*)d_in[2];
    const float* phi1   = (const float*)d_in[3];
    const float* theta1 = (const float*)d_in[4];
    float* out = (float*)d_out;
    float4* coef = (float4*)d_ws;   // 256*1024 float4 = 4 MB

    // coefficients: 256 layers * 2 phases * 512 pairs = 262144 threads
    hipLaunchKernelGGL(eunn_coef_kernel, dim3(1024), dim3(256), 0, stream,
                       phi0, theta0, phi1, theta1, coef);

    // main: 4096 rows / (4 waves/block * RPW rows/wave) = 512 blocks
    hipLaunchKernelGGL(eunn_main_kernel, dim3(512), dim3(256), 0, stream,
                       x, coef, out);
}

// Round 3
// 535.889 us; speedup vs baseline: 2.0626x; 2.0626x over previous
//
#include <hip/hip_runtime.h>

// EUNN: 256 layers; each layer = rotation on even pairs (2i,2i+1), then
// rotation on odd pairs (2i+1,2i+2 mod H).
// Pair math: y0 = e^{i*phi} (ct*u - st*v); y1 = st*u + ct*v.

#define H_DIM 1024
#define C2 256
#define RPW 2   // batch rows per wave

// coef layout: [c][phase][j][lane] as float4 (ct, st, cp, sp), pair i = 8*lane + j
// -> flat float4 index: ((c*2 + phase)*8 + j)*64 + lane,  4 MB total.

__global__ __launch_bounds__(256) void eunn_coef_kernel(
    const float* __restrict__ phi0, const float* __restrict__ theta0,
    const float* __restrict__ phi1, const float* __restrict__ theta1,
    float4* __restrict__ coef) {
    int t = blockIdx.x * 256 + threadIdx.x;     // [0, 256*2*512)
    int i = t & 511;                            // pair index
    int p = (t >> 9) & 1;                       // phase (0: even pairs, 1: odd pairs)
    int c = t >> 10;                            // layer
    const float* phi   = p ? phi1   : phi0;
    const float* theta = p ? theta1 : theta0;
    float ph = phi[i * C2 + c];
    float th = theta[i * C2 + c];
    float sp, cp, st, ct;
    __sincosf(ph, &sp, &cp);
    __sincosf(th, &st, &ct);
    int j = i & 7;
    int l = i >> 3;
    coef[(((c * 2 + p) * 8) + j) * 64 + l] = make_float4(ct, st, cp, sp);
}

__device__ __forceinline__ void rot_pair(const float4 q,
                                         float& ur, float& ui,
                                         float& wr, float& wi) {
    // q = (ct, st, cp, sp)
    float ar = fmaf(-q.y, wr, q.x * ur);   // ct*u - st*v (real part)
    float ai = fmaf(-q.y, wi, q.x * ui);
    float br = fmaf( q.x, wr, q.y * ur);   // st*u + ct*v
    float bi = fmaf( q.x, wi, q.y * ui);
    ur = fmaf(-q.w, ai, q.z * ar);         // e^{i phi} * a
    ui = fmaf( q.w, ar, q.z * ai);
    wr = br;
    wi = bi;
}

__global__ __launch_bounds__(256, 4) void eunn_main_kernel(
    const float* __restrict__ x,
    const float4* __restrict__ coef,
    float* __restrict__ out) {
    const int lane = threadIdx.x & 63;
    const int wave = threadIdx.x >> 6;
    const int row0 = (blockIdx.x * 4 + wave) * RPW;

    // lane owns complex elements [16*lane, 16*lane+16) of each of its RPW rows
    float vr[RPW][16], vi[RPW][16];

#pragma unroll
    for (int r = 0; r < RPW; ++r) {
        const float4* src = (const float4*)(x + (size_t)(row0 + r) * (H_DIM * 2)) + lane * 8;
#pragma unroll
        for (int m = 0; m < 8; ++m) {
            float4 f = src[m];
            vr[r][2 * m]     = f.x; vi[r][2 * m]     = f.y;
            vr[r][2 * m + 1] = f.z; vi[r][2 * m + 1] = f.w;
        }
    }

#pragma unroll 1
    for (int c = 0; c < C2; ++c) {
        const float4* ca = coef + (size_t)c * 1024;

        // --- phase A, boundary-adjacent pairs first (j=0 and j=7) so the
        // cross-lane shuffles can issue early and hide under the FMA work.
        {
            float4 q0 = ca[0 * 64 + lane];
            float4 q7 = ca[7 * 64 + lane];
#pragma unroll
            for (int r = 0; r < RPW; ++r) {
                rot_pair(q0, vr[r][0],  vi[r][0],  vr[r][1],  vi[r][1]);
                rot_pair(q7, vr[r][14], vi[r][14], vr[r][15], vi[r][15]);
            }
        }
        // post-phase-A elem0 / elem15 are final inputs to the phase-B
        // boundary pair; grab neighbors now.
        float nbr[RPW], nbi[RPW], pbr[RPW], pbi[RPW];
#pragma unroll
        for (int r = 0; r < RPW; ++r) {
            nbr[r] = __shfl(vr[r][0],  (lane + 1)  & 63);   // next lane's elem0
            nbi[r] = __shfl(vi[r][0],  (lane + 1)  & 63);
            pbr[r] = __shfl(vr[r][15], (lane + 63) & 63);   // prev lane's elem15
            pbi[r] = __shfl(vi[r][15], (lane + 63) & 63);
        }

        // --- phase A remaining pairs j=1..6
#pragma unroll
        for (int j = 1; j < 7; ++j) {
            float4 q = ca[j * 64 + lane];
#pragma unroll
            for (int r = 0; r < RPW; ++r) {
                rot_pair(q, vr[r][2 * j],     vi[r][2 * j],
                            vr[r][2 * j + 1], vi[r][2 * j + 1]);
            }
        }

        // --- phase B internal pairs (local 2j+1, 2j+2), j=0..6
#pragma unroll
        for (int j = 0; j < 7; ++j) {
            float4 q = ca[(8 + j) * 64 + lane];
#pragma unroll
            for (int r = 0; r < RPW; ++r) {
                rot_pair(q, vr[r][2 * j + 1], vi[r][2 * j + 1],
                            vr[r][2 * j + 2], vi[r][2 * j + 2]);
            }
        }

        // --- phase B boundary pair (my elem15, next lane's elem0): both
        // sides computed locally from the pre-issued shuffles.
        {
            float4 qq = ca[15 * 64 + lane];                  // my boundary coef
            float4 qp = ca[15 * 64 + ((lane + 63) & 63)];    // prev lane's (ct,st)
#pragma unroll
            for (int r = 0; r < RPW; ++r) {
                // new elem15 = e^{i phi}(ct*e15 - st*next_e0)
                float ar = fmaf(-qq.y, nbr[r], qq.x * vr[r][15]);
                float ai = fmaf(-qq.y, nbi[r], qq.x * vi[r][15]);
                vr[r][15] = fmaf(-qq.w, ai, qq.z * ar);
                vi[r][15] = fmaf( qq.w, ar, qq.z * ai);
                // new elem0 = st'*prev_e15 + ct'*e0  (lane-1's pair, second row)
                float b0r = fmaf(qp.x, vr[r][0], qp.y * pbr[r]);
                float b0i = fmaf(qp.x, vi[r][0], qp.y * pbi[r]);
                vr[r][0] = b0r; vi[r][0] = b0i;
            }
        }
    }

#pragma unroll
    for (int r = 0; r < RPW; ++r) {
        float4* dst = (float4*)(out + (size_t)(row0 + r) * (H_DIM * 2)) + lane * 8;
#pragma unroll
        for (int m = 0; m < 8; ++m) {
            dst[m] = make_float4(vr[r][2 * m],     vi[r][2 * m],
                                 vr[r][2 * m + 1], vi[r][2 * m + 1]);
        }
    }
}

extern "C" void kernel_launch(void* const* d_in, const int* in_sizes, int n_in,
                              void* d_out, int out_size, void* d_ws, size_t ws_size,
                              hipStream_t stream) {
    const float* x      = (const float*)d_in[0];
    const float* phi0   = (const float*)d_in[1];
    const float* theta0 = (const float*)d_in[2];
    const float* phi1   = (const float*)d_in[3];
    const float* theta1 = (const float*)d_in[4];
    float* out = (float*)d_out;
    float4* coef = (float4*)d_ws;   // 256*1024 float4 = 4 MB

    // coefficients: 256 layers * 2 phases * 512 pairs = 262144 threads
    hipLaunchKernelGGL(eunn_coef_kernel, dim3(1024), dim3(256), 0, stream,
                       phi0, theta0, phi1, theta1, coef);

    // main: 4096 rows / (4 waves/block * RPW rows/wave) = 512 blocks
    hipLaunchKernelGGL(eunn_main_kernel, dim3(512), dim3(256), 0, stream,
                       x, coef, out);
}

// Round 4
// 426.094 us; speedup vs baseline: 2.5941x; 1.2577x over previous
//
#include <hip/hip_runtime.h>

// EUNN: 256 layers; each layer = rotation on even pairs (2i,2i+1), then
// rotation on odd pairs (2i+1,2i+2 mod H).
// Pair math: y0 = e^{i*phi} (ct*u - st*v); y1 = st*u + ct*v.

#define H_DIM 1024
#define C2 256
#define RPW 2   // batch rows per wave

// coef layout: [c][phase][j][lane] as float4 (ct, st, cp, sp), pair i = 8*lane + j
// -> flat float4 index: ((c*2 + phase)*8 + j)*64 + lane,  4 MB total.

__global__ __launch_bounds__(256) void eunn_coef_kernel(
    const float* __restrict__ phi0, const float* __restrict__ theta0,
    const float* __restrict__ phi1, const float* __restrict__ theta1,
    float4* __restrict__ coef) {
    int t = blockIdx.x * 256 + threadIdx.x;     // [0, 256*2*512)
    int i = t & 511;                            // pair index
    int p = (t >> 9) & 1;                       // phase (0: even pairs, 1: odd pairs)
    int c = t >> 10;                            // layer
    const float* phi   = p ? phi1   : phi0;
    const float* theta = p ? theta1 : theta0;
    float ph = phi[i * C2 + c];
    float th = theta[i * C2 + c];
    float sp, cp, st, ct;
    __sincosf(ph, &sp, &cp);
    __sincosf(th, &st, &ct);
    int j = i & 7;
    int l = i >> 3;
    coef[(((c * 2 + p) * 8) + j) * 64 + l] = make_float4(ct, st, cp, sp);
}

__device__ __forceinline__ void rot_pair(const float4 q,
                                         float& ur, float& ui,
                                         float& wr, float& wi) {
    // q = (ct, st, cp, sp)
    float ar = fmaf(-q.y, wr, q.x * ur);   // ct*u - st*v (real part)
    float ai = fmaf(-q.y, wi, q.x * ui);
    float br = fmaf( q.x, wr, q.y * ur);   // st*u + ct*v
    float bi = fmaf( q.x, wi, q.y * ui);
    ur = fmaf(-q.w, ai, q.z * ar);         // e^{i phi} * a
    ui = fmaf( q.w, ar, q.z * ai);
    wr = br;
    wi = bi;
}

// NOTE (R3 post-mortem): do NOT add a min-waves arg to launch_bounds here.
// (256,4) capped VGPRs at 128 and the compiler squeezed to 64 arch VGPRs,
// shuffling the 64-float state through extra moves -> 526us. (256,2)-style
// default gives the clean ~128-VGPR allocation (R1: 423us codegen).
__global__ __launch_bounds__(256, 2) void eunn_main_kernel(
    const float* __restrict__ x,
    const float4* __restrict__ coef,
    float* __restrict__ out) {
    const int lane = threadIdx.x & 63;
    const int wave = threadIdx.x >> 6;
    const int row0 = (blockIdx.x * 4 + wave) * RPW;

    // lane owns complex elements [16*lane, 16*lane+16) of each of its RPW rows
    float vr[RPW][16], vi[RPW][16];

#pragma unroll
    for (int r = 0; r < RPW; ++r) {
        const float4* src = (const float4*)(x + (size_t)(row0 + r) * (H_DIM * 2)) + lane * 8;
#pragma unroll
        for (int m = 0; m < 8; ++m) {
            float4 f = src[m];
            vr[r][2 * m]     = f.x; vi[r][2 * m]     = f.y;
            vr[r][2 * m + 1] = f.z; vi[r][2 * m + 1] = f.w;
        }
    }

    const float4* cl = coef + lane;   // lane-offset base, strength-reduced in loop

#pragma unroll 1
    for (int c = 0; c < C2; ++c) {
        const float4* ca = cl + (size_t)c * 1024;

        // boundary coef for phase B, loaded up front; prev-lane copy via
        // shuffle (cheaper than a second VMEM with rotated addressing).
        float4 qq = ca[15 * 64];
        float qpx = __shfl(qq.x, (lane + 63) & 63);   // prev lane's ct'
        float qpy = __shfl(qq.y, (lane + 63) & 63);   // prev lane's st'

        // --- phase A, boundary-adjacent pairs first (j=0 and j=7) so the
        // cross-lane shuffles can issue early and hide under the FMA work.
        {
            float4 q0 = ca[0 * 64];
            float4 q7 = ca[7 * 64];
#pragma unroll
            for (int r = 0; r < RPW; ++r) {
                rot_pair(q0, vr[r][0],  vi[r][0],  vr[r][1],  vi[r][1]);
                rot_pair(q7, vr[r][14], vi[r][14], vr[r][15], vi[r][15]);
            }
        }
        // post-phase-A elem0 / elem15 are the inputs to the phase-B
        // boundary pair; grab neighbors now.
        float nbr[RPW], nbi[RPW], pbr[RPW], pbi[RPW];
#pragma unroll
        for (int r = 0; r < RPW; ++r) {
            nbr[r] = __shfl(vr[r][0],  (lane + 1)  & 63);   // next lane's elem0
            nbi[r] = __shfl(vi[r][0],  (lane + 1)  & 63);
            pbr[r] = __shfl(vr[r][15], (lane + 63) & 63);   // prev lane's elem15
            pbi[r] = __shfl(vi[r][15], (lane + 63) & 63);
        }

        // --- phase A remaining pairs j=1..6
#pragma unroll
        for (int j = 1; j < 7; ++j) {
            float4 q = ca[j * 64];
#pragma unroll
            for (int r = 0; r < RPW; ++r) {
                rot_pair(q, vr[r][2 * j],     vi[r][2 * j],
                            vr[r][2 * j + 1], vi[r][2 * j + 1]);
            }
        }

        // --- phase B internal pairs (local 2j+1, 2j+2), j=0..6
#pragma unroll
        for (int j = 0; j < 7; ++j) {
            float4 q = ca[(8 + j) * 64];
#pragma unroll
            for (int r = 0; r < RPW; ++r) {
                rot_pair(q, vr[r][2 * j + 1], vi[r][2 * j + 1],
                            vr[r][2 * j + 2], vi[r][2 * j + 2]);
            }
        }

        // --- phase B boundary pair (my elem15, next lane's elem0): both
        // sides computed locally from the pre-issued shuffles.
#pragma unroll
        for (int r = 0; r < RPW; ++r) {
            // new elem15 = e^{i phi}(ct*e15 - st*next_e0)
            float ar = fmaf(-qq.y, nbr[r], qq.x * vr[r][15]);
            float ai = fmaf(-qq.y, nbi[r], qq.x * vi[r][15]);
            vr[r][15] = fmaf(-qq.w, ai, qq.z * ar);
            vi[r][15] = fmaf( qq.w, ar, qq.z * ai);
            // new elem0 = st'*prev_e15 + ct'*e0  (lane-1's pair, second row)
            float b0r = fmaf(qpx, vr[r][0], qpy * pbr[r]);
            float b0i = fmaf(qpx, vi[r][0], qpy * pbi[r]);
            vr[r][0] = b0r; vi[r][0] = b0i;
        }
    }

#pragma unroll
    for (int r = 0; r < RPW; ++r) {
        float4* dst = (float4*)(out + (size_t)(row0 + r) * (H_DIM * 2)) + lane * 8;
#pragma unroll
        for (int m = 0; m < 8; ++m) {
            dst[m] = make_float4(vr[r][2 * m],     vi[r][2 * m],
                                 vr[r][2 * m + 1], vi[r][2 * m + 1]);
        }
    }
}

extern "C" void kernel_launch(void* const* d_in, const int* in_sizes, int n_in,
                              void* d_out, int out_size, void* d_ws, size_t ws_size,
                              hipStream_t stream) {
    const float* x      = (const float*)d_in[0];
    const float* phi0   = (const float*)d_in[1];
    const float* theta0 = (const float*)d_in[2];
    const float* phi1   = (const float*)d_in[3];
    const float* theta1 = (const float*)d_in[4];
    float* out = (float*)d_out;
    float4* coef = (float4*)d_ws;   // 256*1024 float4 = 4 MB

    // coefficients: 256 layers * 2 phases * 512 pairs = 262144 threads
    hipLaunchKernelGGL(eunn_coef_kernel, dim3(1024), dim3(256), 0, stream,
                       phi0, theta0, phi1, theta1, coef);

    // main: 4096 rows / (4 waves/block * RPW rows/wave) = 512 blocks
    hipLaunchKernelGGL(eunn_main_kernel, dim3(512), dim3(256), 0, stream,
                       x, coef, out);
}